// Round 9
// baseline (22591.403 us; speedup 1.0000x reference)
//
#include <hip/hip_runtime.h>
#include <hip/hip_cooperative_groups.h>

// Problem constants (match reference)
#define TSTEPS 500
#define NB     64
#define NINP   64
#define NHID   1024
#define NOUTV  3
#define ALPHA_F 0.1f

// Recurrent kernel geometry
#define NWG    128
#define NTHR   256
#define CJ     32
#define NCH    8

#define AUX_COH 0x11   // SC0|SC1: bypass L1 + non-coherent L2, read from coherent point

// Real state
__device__ float    g_rT[2 * NHID * NB];
__device__ unsigned g_bar[TSTEPS + 1];
__device__ unsigned g_epochs[NWG];
// Probe-only state (never touches outputs)
__device__ float    g_rT2[2 * NHID * NB];
__device__ unsigned g_bar2[TSTEPS + 1];
__device__ unsigned g_epochs2[NWG];

__device__ __forceinline__ void grid_barrier_on(unsigned* slot, unsigned target, int tid) {
    asm volatile("s_waitcnt vmcnt(0)" ::: "memory");
    __syncthreads();
    if (tid == 0) {
        __hip_atomic_fetch_add(slot, 1u, __ATOMIC_RELAXED, __HIP_MEMORY_SCOPE_AGENT);
        long long t0 = clock64();
        while (__hip_atomic_load(slot, __ATOMIC_RELAXED, __HIP_MEMORY_SCOPE_AGENT) < target) {
            __builtin_amdgcn_s_sleep(4);
            if (clock64() - t0 > 400000000LL) break;
        }
    }
    __syncthreads();
}

// ---------------------------------------------------------------------------
// MAIN kernel — byte-identical logic to R8 (passed; 8.39 ms dispatch)
// ---------------------------------------------------------------------------
__global__ __launch_bounds__(NTHR)
void rnn_loop_kernel(const float* __restrict__ X,
                     const float* __restrict__ hidden1,
                     const float* __restrict__ Wih,
                     const float* __restrict__ Whh,
                     float* __restrict__ hid_out)
{
    __shared__ float sbuf[4][2][CJ * NB];
    __shared__ float redbuf[4 * 8 * NB];
    __shared__ float sred2[8 * NB];
    __shared__ unsigned s_epoch;

    const int tid  = threadIdx.x;
    const int lane = tid & 63;
    const int w    = __builtin_amdgcn_readfirstlane(tid >> 6);
    const int g    = blockIdx.x;
    const int hq   = g * 8;
    const int jq   = w * 256;
    const int i0   = 2 * w, i1 = 2 * w + 1;
    const int h0   = hq + i0, h1 = hq + i1;

    if (tid == 0) {
        unsigned e = __hip_atomic_load(&g_epochs[g], __ATOMIC_RELAXED, __HIP_MEMORY_SCOPE_AGENT) + 1;
        __hip_atomic_store(&g_epochs[g], e, __ATOMIC_RELAXED, __HIP_MEMORY_SCOPE_AGENT);
        s_epoch = e;
    }
    __syncthreads();
    const unsigned target = s_epoch * NWG;

    const float* wr0 = Whh + (size_t)(hq + 0) * NHID;
    const float* wr1 = Whh + (size_t)(hq + 1) * NHID;
    const float* wr2 = Whh + (size_t)(hq + 2) * NHID;
    const float* wr3 = Whh + (size_t)(hq + 3) * NHID;
    const float* wr4 = Whh + (size_t)(hq + 4) * NHID;
    const float* wr5 = Whh + (size_t)(hq + 5) * NHID;
    const float* wr6 = Whh + (size_t)(hq + 6) * NHID;
    const float* wr7 = Whh + (size_t)(hq + 7) * NHID;
    const float* wih0 = Wih + (size_t)h0 * NINP;
    const float* wih1 = Wih + (size_t)h1 * NINP;

    float x0 = hidden1[(size_t)lane * NHID + h0];
    float x1 = hidden1[(size_t)lane * NHID + h1];
    float r0 = tanhf(x0);
    float r1 = tanhf(x1);
    __hip_atomic_store(&g_rT[(size_t)h0 * NB + lane], r0, __ATOMIC_RELAXED, __HIP_MEMORY_SCOPE_AGENT);
    __hip_atomic_store(&g_rT[(size_t)h1 * NB + lane], r1, __ATOMIC_RELAXED, __HIP_MEMORY_SCOPE_AGENT);
    grid_barrier_on(&g_bar[0], target, tid);

    int p = 0;
    for (int t = 0; t < TSTEPS; ++t) {
        const float* rsrc = g_rT + (size_t)p * NHID * NB;

        {
            const char* gsrc = (const char*)(rsrc + (size_t)jq * NB);
            char* lbase = (char*)&sbuf[w][0][0];
            #pragma unroll
            for (int q = 0; q < 8; ++q) {
                __builtin_amdgcn_global_load_lds(
                    (const __attribute__((address_space(1))) void*)(gsrc + q * 1024 + lane * 16),
                    (__attribute__((address_space(3))) void*)(lbase + q * 1024),
                    16, 0, AUX_COH);
            }
        }

        float a0 = 0.f, a1 = 0.f, a2 = 0.f, a3 = 0.f;
        float a4 = 0.f, a5 = 0.f, a6 = 0.f, a7 = 0.f;

        #pragma unroll 1
        for (int k = 0; k < NCH; ++k) {
            if (k + 1 < NCH) {
                const char* gsrc = (const char*)(rsrc + (size_t)(jq + (k + 1) * CJ) * NB);
                char* lbase = (char*)&sbuf[w][(k + 1) & 1][0];
                #pragma unroll
                for (int q = 0; q < 8; ++q) {
                    __builtin_amdgcn_global_load_lds(
                        (const __attribute__((address_space(1))) void*)(gsrc + q * 1024 + lane * 16),
                        (__attribute__((address_space(3))) void*)(lbase + q * 1024),
                        16, 0, AUX_COH);
                }
                asm volatile("s_waitcnt vmcnt(8)" ::: "memory");
            } else {
                asm volatile("s_waitcnt vmcnt(0)" ::: "memory");
            }

            const float* buf = &sbuf[w][k & 1][0];
            const int jb = jq + k * CJ;
            #pragma unroll 8
            for (int j = 0; j < CJ; ++j) {
                float rv = buf[j * NB + lane];
                a0 = fmaf(wr0[jb + j], rv, a0);
                a1 = fmaf(wr1[jb + j], rv, a1);
                a2 = fmaf(wr2[jb + j], rv, a2);
                a3 = fmaf(wr3[jb + j], rv, a3);
                a4 = fmaf(wr4[jb + j], rv, a4);
                a5 = fmaf(wr5[jb + j], rv, a5);
                a6 = fmaf(wr6[jb + j], rv, a6);
                a7 = fmaf(wr7[jb + j], rv, a7);
            }
        }

        redbuf[(w * 8 + 0) * NB + lane] = a0;
        redbuf[(w * 8 + 1) * NB + lane] = a1;
        redbuf[(w * 8 + 2) * NB + lane] = a2;
        redbuf[(w * 8 + 3) * NB + lane] = a3;
        redbuf[(w * 8 + 4) * NB + lane] = a4;
        redbuf[(w * 8 + 5) * NB + lane] = a5;
        redbuf[(w * 8 + 6) * NB + lane] = a6;
        redbuf[(w * 8 + 7) * NB + lane] = a7;
        __syncthreads();
        float dot0 = redbuf[(0 * 8 + i0) * NB + lane] + redbuf[(1 * 8 + i0) * NB + lane]
                   + redbuf[(2 * 8 + i0) * NB + lane] + redbuf[(3 * 8 + i0) * NB + lane];
        float dot1 = redbuf[(0 * 8 + i1) * NB + lane] + redbuf[(1 * 8 + i1) * NB + lane]
                   + redbuf[(2 * 8 + i1) * NB + lane] + redbuf[(3 * 8 + i1) * NB + lane];

        float xw0 = 0.f, xw1 = 0.f;
        const float4* xp = (const float4*)(X + ((size_t)t * NB + lane) * NINP);
        #pragma unroll
        for (int i = 0; i < NINP / 4; ++i) {
            float4 v = xp[i];
            xw0 = fmaf(wih0[4 * i + 0], v.x, xw0); xw1 = fmaf(wih1[4 * i + 0], v.x, xw1);
            xw0 = fmaf(wih0[4 * i + 1], v.y, xw0); xw1 = fmaf(wih1[4 * i + 1], v.y, xw1);
            xw0 = fmaf(wih0[4 * i + 2], v.z, xw0); xw1 = fmaf(wih1[4 * i + 2], v.z, xw1);
            xw0 = fmaf(wih0[4 * i + 3], v.w, xw0); xw1 = fmaf(wih1[4 * i + 3], v.w, xw1);
        }

        x0 = fmaf(ALPHA_F, dot0 + xw0 - x0, x0);
        x1 = fmaf(ALPHA_F, dot1 + xw1 - x1, x1);
        r0 = tanhf(x0);
        r1 = tanhf(x1);

        {
            float* rdst = g_rT + (size_t)(p ^ 1) * NHID * NB;
            __hip_atomic_store(&rdst[(size_t)h0 * NB + lane], r0, __ATOMIC_RELAXED, __HIP_MEMORY_SCOPE_AGENT);
            __hip_atomic_store(&rdst[(size_t)h1 * NB + lane], r1, __ATOMIC_RELAXED, __HIP_MEMORY_SCOPE_AGENT);
        }

        sred2[i0 * NB + lane] = r0;
        sred2[i1 * NB + lane] = r1;
        __syncthreads();
        if (w < 2) {
            float4 v;
            v.x = sred2[(4 * w + 0) * NB + lane];
            v.y = sred2[(4 * w + 1) * NB + lane];
            v.z = sred2[(4 * w + 2) * NB + lane];
            v.w = sred2[(4 * w + 3) * NB + lane];
            *(float4*)(hid_out + ((size_t)t * NB + lane) * NHID + hq + 4 * w) = v;
        }

        grid_barrier_on(&g_bar[t + 1], target, tid);
        p ^= 1;
    }
}

// ---------------------------------------------------------------------------
// PROBE 1: barrier-only. 500 fence-free grid barriers, zero work.
// ---------------------------------------------------------------------------
__global__ __launch_bounds__(NTHR)
void probe_barrier()
{
    __shared__ unsigned s_epoch;
    const int tid = threadIdx.x;
    const int g   = blockIdx.x;
    if (tid == 0) {
        unsigned e = __hip_atomic_load(&g_epochs2[g], __ATOMIC_RELAXED, __HIP_MEMORY_SCOPE_AGENT) + 1;
        __hip_atomic_store(&g_epochs2[g], e, __ATOMIC_RELAXED, __HIP_MEMORY_SCOPE_AGENT);
        s_epoch = e;
    }
    __syncthreads();
    const unsigned target = s_epoch * NWG;
    for (int t = 0; t <= TSTEPS; ++t)
        grid_barrier_on(&g_bar2[t], target, tid);
}

// ---------------------------------------------------------------------------
// PROBE 2/3: full step body (stage + FMA + LDS reduce + X proj + tanh),
// no barrier, no global stores. Template on cache-policy aux.
// ---------------------------------------------------------------------------
template<int AUX>
__global__ __launch_bounds__(NTHR)
void probe_stage(const float* __restrict__ X,
                 const float* __restrict__ Wih,
                 const float* __restrict__ Whh)
{
    __shared__ float sbuf[4][2][CJ * NB];
    __shared__ float redbuf[4 * 8 * NB];

    const int tid  = threadIdx.x;
    const int lane = tid & 63;
    const int w    = __builtin_amdgcn_readfirstlane(tid >> 6);
    const int g    = blockIdx.x;
    const int hq   = g * 8;
    const int jq   = w * 256;
    const int i0   = 2 * w, i1 = 2 * w + 1;

    const float* wr0 = Whh + (size_t)(hq + 0) * NHID;
    const float* wr1 = Whh + (size_t)(hq + 1) * NHID;
    const float* wr2 = Whh + (size_t)(hq + 2) * NHID;
    const float* wr3 = Whh + (size_t)(hq + 3) * NHID;
    const float* wr4 = Whh + (size_t)(hq + 4) * NHID;
    const float* wr5 = Whh + (size_t)(hq + 5) * NHID;
    const float* wr6 = Whh + (size_t)(hq + 6) * NHID;
    const float* wr7 = Whh + (size_t)(hq + 7) * NHID;
    const float* wih0 = Wih + (size_t)(hq + i0) * NINP;
    const float* wih1 = Wih + (size_t)(hq + i1) * NINP;

    float x0 = 0.f, x1 = 0.f;
    int p = 0;
    for (int t = 0; t < TSTEPS; ++t) {
        const float* rsrc = g_rT2 + (size_t)p * NHID * NB;
        {
            const char* gsrc = (const char*)(rsrc + (size_t)jq * NB);
            char* lbase = (char*)&sbuf[w][0][0];
            #pragma unroll
            for (int q = 0; q < 8; ++q) {
                if constexpr (AUX == 0)
                    __builtin_amdgcn_global_load_lds(
                        (const __attribute__((address_space(1))) void*)(gsrc + q * 1024 + lane * 16),
                        (__attribute__((address_space(3))) void*)(lbase + q * 1024), 16, 0, 0);
                else
                    __builtin_amdgcn_global_load_lds(
                        (const __attribute__((address_space(1))) void*)(gsrc + q * 1024 + lane * 16),
                        (__attribute__((address_space(3))) void*)(lbase + q * 1024), 16, 0, AUX_COH);
            }
        }

        float a0 = 0.f, a1 = 0.f, a2 = 0.f, a3 = 0.f;
        float a4 = 0.f, a5 = 0.f, a6 = 0.f, a7 = 0.f;

        #pragma unroll 1
        for (int k = 0; k < NCH; ++k) {
            if (k + 1 < NCH) {
                const char* gsrc = (const char*)(rsrc + (size_t)(jq + (k + 1) * CJ) * NB);
                char* lbase = (char*)&sbuf[w][(k + 1) & 1][0];
                #pragma unroll
                for (int q = 0; q < 8; ++q) {
                    if constexpr (AUX == 0)
                        __builtin_amdgcn_global_load_lds(
                            (const __attribute__((address_space(1))) void*)(gsrc + q * 1024 + lane * 16),
                            (__attribute__((address_space(3))) void*)(lbase + q * 1024), 16, 0, 0);
                    else
                        __builtin_amdgcn_global_load_lds(
                            (const __attribute__((address_space(1))) void*)(gsrc + q * 1024 + lane * 16),
                            (__attribute__((address_space(3))) void*)(lbase + q * 1024), 16, 0, AUX_COH);
                }
                asm volatile("s_waitcnt vmcnt(8)" ::: "memory");
            } else {
                asm volatile("s_waitcnt vmcnt(0)" ::: "memory");
            }

            const float* buf = &sbuf[w][k & 1][0];
            const int jb = jq + k * CJ;
            #pragma unroll 8
            for (int j = 0; j < CJ; ++j) {
                float rv = buf[j * NB + lane];
                a0 = fmaf(wr0[jb + j], rv, a0);
                a1 = fmaf(wr1[jb + j], rv, a1);
                a2 = fmaf(wr2[jb + j], rv, a2);
                a3 = fmaf(wr3[jb + j], rv, a3);
                a4 = fmaf(wr4[jb + j], rv, a4);
                a5 = fmaf(wr5[jb + j], rv, a5);
                a6 = fmaf(wr6[jb + j], rv, a6);
                a7 = fmaf(wr7[jb + j], rv, a7);
            }
        }

        redbuf[(w * 8 + 0) * NB + lane] = a0;
        redbuf[(w * 8 + 1) * NB + lane] = a1;
        redbuf[(w * 8 + 2) * NB + lane] = a2;
        redbuf[(w * 8 + 3) * NB + lane] = a3;
        redbuf[(w * 8 + 4) * NB + lane] = a4;
        redbuf[(w * 8 + 5) * NB + lane] = a5;
        redbuf[(w * 8 + 6) * NB + lane] = a6;
        redbuf[(w * 8 + 7) * NB + lane] = a7;
        __syncthreads();
        float dot0 = redbuf[(0 * 8 + i0) * NB + lane] + redbuf[(1 * 8 + i0) * NB + lane]
                   + redbuf[(2 * 8 + i0) * NB + lane] + redbuf[(3 * 8 + i0) * NB + lane];
        float dot1 = redbuf[(0 * 8 + i1) * NB + lane] + redbuf[(1 * 8 + i1) * NB + lane]
                   + redbuf[(2 * 8 + i1) * NB + lane] + redbuf[(3 * 8 + i1) * NB + lane];
        __syncthreads();

        float xw0 = 0.f, xw1 = 0.f;
        const float4* xp = (const float4*)(X + ((size_t)t * NB + lane) * NINP);
        #pragma unroll
        for (int i = 0; i < NINP / 4; ++i) {
            float4 v = xp[i];
            xw0 = fmaf(wih0[4 * i + 0], v.x, xw0); xw1 = fmaf(wih1[4 * i + 0], v.x, xw1);
            xw0 = fmaf(wih0[4 * i + 1], v.y, xw0); xw1 = fmaf(wih1[4 * i + 1], v.y, xw1);
            xw0 = fmaf(wih0[4 * i + 2], v.z, xw0); xw1 = fmaf(wih1[4 * i + 2], v.z, xw1);
            xw0 = fmaf(wih0[4 * i + 3], v.w, xw0); xw1 = fmaf(wih1[4 * i + 3], v.w, xw1);
        }

        x0 = fmaf(ALPHA_F, dot0 + xw0 - x0, x0);
        x1 = fmaf(ALPHA_F, dot1 + xw1 - x1, x1);
        x0 = tanhf(x0);
        x1 = tanhf(x1);
        p ^= 1;
    }
    // keep the whole computation live without any store (rule #17)
    asm volatile("" :: "v"(x0), "v"(x1));
}

// ---------------------------------------------------------------------------
__global__ __launch_bounds__(256)
void out_proj_kernel(const float* __restrict__ hid,
                     const float* __restrict__ perturb,
                     const float* __restrict__ Wout,
                     const float* __restrict__ bout,
                     float* __restrict__ outv,
                     float* __restrict__ outp)
{
    const int gw   = (int)((blockIdx.x * blockDim.x + threadIdx.x) >> 6);
    const int lane = threadIdx.x & 63;
    if (gw >= TSTEPS * NB) return;

    const float4* r4  = (const float4*)(hid + (size_t)gw * NHID);
    const float4* w04 = (const float4*)(Wout);
    const float4* w14 = (const float4*)(Wout + NHID);
    const float4* w24 = (const float4*)(Wout + 2 * NHID);

    float s0 = 0.f, s1 = 0.f, s2 = 0.f;
    #pragma unroll
    for (int q = 0; q < 4; ++q) {
        int idx = lane * 4 + q;
        float4 v = r4[idx];
        float4 a = w04[idx]; s0 += v.x * a.x + v.y * a.y + v.z * a.z + v.w * a.w;
        float4 b = w14[idx]; s1 += v.x * b.x + v.y * b.y + v.z * b.z + v.w * b.w;
        float4 c = w24[idx]; s2 += v.x * c.x + v.y * c.y + v.z * c.z + v.w * c.w;
    }
    #pragma unroll
    for (int m = 1; m < 64; m <<= 1) {
        s0 += __shfl_xor(s0, m, 64);
        s1 += __shfl_xor(s1, m, 64);
        s2 += __shfl_xor(s2, m, 64);
    }
    if (lane == 0) {
        float o0 = s0 + bout[0];
        float o1 = s1 + bout[1];
        float o2 = s2 + bout[2];
        float* ov = outv + (size_t)gw * 3;
        ov[0] = o0; ov[1] = o1; ov[2] = o2;
        const float* pj = perturb + (size_t)gw * 9;
        float* op = outp + (size_t)gw * 3;
        op[0] = pj[0] * o0 + pj[1] * o1 + pj[2] * o2;
        op[1] = pj[3] * o0 + pj[4] * o1 + pj[5] * o2;
        op[2] = pj[6] * o0 + pj[7] * o1 + pj[8] * o2;
    }
}

// ---------------------------------------------------------------------------
extern "C" void kernel_launch(void* const* d_in, const int* in_sizes, int n_in,
                              void* d_out, int out_size, void* d_ws, size_t ws_size,
                              hipStream_t stream)
{
    const float* X       = (const float*)d_in[0];
    const float* perturb = (const float*)d_in[1];
    const float* hidden1 = (const float*)d_in[2];
    const float* Wih     = (const float*)d_in[3];
    const float* Whh     = (const float*)d_in[4];
    const float* Wout    = (const float*)d_in[5];
    const float* bout    = (const float*)d_in[6];

    float* out  = (float*)d_out;
    float* outv = out;
    float* outp = out + (size_t)TSTEPS * NB * NOUTV;
    float* hid  = out + (size_t)2 * TSTEPS * NB * NOUTV;

    void* args[] = { (void*)&X, (void*)&hidden1, (void*)&Wih, (void*)&Whh,
                     (void*)&hid };
    hipLaunchCooperativeKernel((void*)rnn_loop_kernel, dim3(NWG), dim3(NTHR),
                               args, 0, stream);

    out_proj_kernel<<<dim3((TSTEPS * NB) / 4), dim3(256), 0, stream>>>(
        hid, perturb, Wout, bout, outv, outp);

    // ---- probes (profiling only; no output writes) ----
    void* bargs[] = {};
    hipLaunchCooperativeKernel((void*)probe_barrier, dim3(NWG), dim3(NTHR),
                               bargs, 0, stream);
    probe_stage<AUX_COH><<<dim3(NWG), dim3(NTHR), 0, stream>>>(X, Wih, Whh);
    probe_stage<0><<<dim3(NWG), dim3(NTHR), 0, stream>>>(X, Wih, Whh);
}